// Round 3
// baseline (186.768 us; speedup 1.0000x reference)
//
#include <hip/hip_runtime.h>

constexpr int NTOT   = 13;
constexpr int DIM    = 1 << NTOT;   // 8192
constexpr int DDATA  = DIM / 2;     // 4096
constexpr int LAYERS = 6;
constexpr int NGATES = LAYERS * NTOT; // 78
constexpr int BLOCK  = 1024;

// Per-gate coefficients from params.
// U = RY@RX = [[A+iB, -C-iD], [C-iD, A-iB]], A=cy*cx, B=sy*sx, C=sy*cx, D=cy*sx.
__global__ void gates_precompute(const float* __restrict__ params,
                                 float* __restrict__ gates) {
    int t = threadIdx.x;
    if (t >= NGATES) return;
    int l = t / NTOT, q = t % NTOT;
    float tx = params[2 * NTOT * l + q];
    float ty = params[2 * NTOT * l + NTOT + q];
    float sx, cx, sy, cy;
    sincosf(0.5f * tx, &sx, &cx);
    sincosf(0.5f * ty, &sy, &cy);
    gates[4 * t + 0] = cy * cx;
    gates[4 * t + 1] = sy * sx;
    gates[4 * t + 2] = sy * cx;
    gates[4 * t + 3] = cy * sx;
}

// Bijective LDS swizzle (involution): XOR bits 3:1 with bits 6:4.
// Makes every pass's ds_read_b64 pattern hit each bank exactly 4x (= minimum).
__device__ __forceinline__ int swz(int idx) { return idx ^ (((idx >> 4) & 7) << 1); }

__device__ __forceinline__ void gate_pair(float2& va, float2& vb,
                                          float A, float B, float C, float D) {
    float ar = va.x, ai = va.y, br = vb.x, bi = vb.y;
    va.x = A * ar - B * ai - C * br + D * bi;
    va.y = B * ar + A * ai - D * br - C * bi;
    vb.x = C * ar + D * ai + A * br + B * bi;
    vb.y = C * ai - D * ar + A * bi - B * br;
}

// One LDS round trip applying 3 gates (qubits qbase..qbase+2 <-> index bits S+2..S).
// If LAST: also apply qubit 12 (index bit 0 == lane bit 0, via shfl_xor) and the
// brickwork-CZ diagonal sign (-1)^popc(idx & idx>>1).
template<int S, bool LAST>
__device__ __forceinline__ void do_pass(float2* s, const float* __restrict__ g,
                                        int l, int qbase, int p) {
    const int base = ((p >> S) << (S + 3)) | (p & ((1 << S) - 1));
    float2 v[8];
    int addr[8];
    #pragma unroll
    for (int m = 0; m < 8; ++m) {
        addr[m] = swz(base | (m << S));
        v[m] = s[addr[m]];
    }
    #pragma unroll
    for (int c = 0; c < 3; ++c) {
        const float* gp = g + 4 * (l * NTOT + qbase + c);
        const float A = gp[0], B = gp[1], C = gp[2], D = gp[3];
        const int lb = 4 >> c;          // qubit qbase+c acts on local bit 2-c
        #pragma unroll
        for (int m = 0; m < 8; ++m)
            if (!(m & lb)) gate_pair(v[m], v[m | lb], A, B, C, D);
    }
    if (LAST) {
        const float* gp = g + 4 * (l * NTOT + 12);
        const float A = gp[0], B = gp[1], C = gp[2], D = gp[3];
        const int odd = p & 1;          // idx bit 0 == lane bit 0 when S==1
        const float Bs = odd ? -B : B;  // new = (A+i*Bs)*mine + (Cq - i*D)*partner
        const float Cq = odd ? C : -C;
        #pragma unroll
        for (int m = 0; m < 8; ++m) {
            float vr = v[m].x, vi = v[m].y;
            float pr = __shfl_xor(vr, 1, 64);
            float pi = __shfl_xor(vi, 1, 64);
            float nr = A * vr - Bs * vi + Cq * pr + D * pi;
            float ni = A * vi + Bs * vr + Cq * pi - D * pr;
            int idx = base | (m << S);
            float sg = 1.0f - 2.0f * (float)(__popc(idx & (idx >> 1)) & 1);
            v[m].x = nr * sg;
            v[m].y = ni * sg;
        }
    }
    #pragma unroll
    for (int m = 0; m < 8; ++m) s[addr[m]] = v[m];
}

__global__ __launch_bounds__(BLOCK)
void qddpm_main(const float* __restrict__ re_in, const float* __restrict__ im_in,
                const int* __restrict__ m_res, const float* __restrict__ g,
                float* __restrict__ out) {
    __shared__ float2 s[DIM];          // exactly 64 KB static LDS
    const int b = blockIdx.x;
    const int t = threadIdx.x;

    // Coalesced load, interleave re/im into LDS (swizzled positions).
    const float4* re4 = reinterpret_cast<const float4*>(re_in + (size_t)b * DIM);
    const float4* im4 = reinterpret_cast<const float4*>(im_in + (size_t)b * DIM);
    #pragma unroll
    for (int k = 0; k < DIM / 4 / BLOCK; ++k) {   // 2 iterations
        int e = t + k * BLOCK;
        float4 r = re4[e];
        float4 i = im4[e];
        s[swz(4 * e + 0)] = make_float2(r.x, i.x);
        s[swz(4 * e + 1)] = make_float2(r.y, i.y);
        s[swz(4 * e + 2)] = make_float2(r.z, i.z);
        s[swz(4 * e + 3)] = make_float2(r.w, i.w);
    }
    __syncthreads();

    for (int l = 0; l < LAYERS; ++l) {
        do_pass<10, false>(s, g, l, 0, t); __syncthreads();  // qubits 0,1,2  (bits 12:10)
        do_pass<7,  false>(s, g, l, 3, t); __syncthreads();  // qubits 3,4,5  (bits 9:7)
        do_pass<4,  false>(s, g, l, 6, t); __syncthreads();  // qubits 6,7,8  (bits 6:4)
        do_pass<1,  true >(s, g, l, 9, t); __syncthreads();  // qubits 9..12 + CZ (bits 3:0)
    }

    // Post-select ancilla (MSB) per m_res, normalize, write [DDATA][2] f32.
    const int off = (m_res[b] == 0) ? 0 : DDATA;
    float2 v[4];
    float acc = 0.f;
    #pragma unroll
    for (int u = 0; u < 4; ++u) {
        v[u] = s[swz(off + 4 * t + u)];
        acc += v[u].x * v[u].x + v[u].y * v[u].y;
    }
    #pragma unroll
    for (int o = 32; o > 0; o >>= 1) acc += __shfl_down(acc, o, 64);
    __syncthreads();                    // all gather-reads done; state LDS now dead
    float* red = reinterpret_cast<float*>(s);
    if ((t & 63) == 0) red[t >> 6] = acc;
    __syncthreads();
    if (t == 0) {
        float tot = 0.f;
        #pragma unroll
        for (int w = 0; w < BLOCK / 64; ++w) tot += red[w];
        red[16] = rsqrtf(tot);
    }
    __syncthreads();
    const float sc = red[16];
    float4* o4 = reinterpret_cast<float4*>(out + (size_t)b * DDATA * 2);
    o4[2 * t + 0] = make_float4(v[0].x * sc, v[0].y * sc, v[1].x * sc, v[1].y * sc);
    o4[2 * t + 1] = make_float4(v[2].x * sc, v[2].y * sc, v[3].x * sc, v[3].y * sc);
}

extern "C" void kernel_launch(void* const* d_in, const int* in_sizes, int n_in,
                              void* d_out, int out_size, void* d_ws, size_t ws_size,
                              hipStream_t stream) {
    const float* re     = (const float*)d_in[0];
    const float* im     = (const float*)d_in[1];
    const float* params = (const float*)d_in[2];
    const int*   mres   = (const int*)d_in[3];
    float* out   = (float*)d_out;
    float* gates = (float*)d_ws;   // 78*4 floats = 1248 B

    const int B = in_sizes[3];     // 512

    gates_precompute<<<1, 128, 0, stream>>>(params, gates);
    qddpm_main<<<B, BLOCK, 0, stream>>>(re, im, mres, gates, out);
}